// Round 12
// baseline (99.378 us; speedup 1.0000x reference)
//
#include <hip/hip_runtime.h>

// Problem constants
#define D_K   1024      // hidden dim (GEMM K)
#define ROWS  16384     // B*L
#define MLP   500
#define NEG   0.01f

// GEMM geometry: 256x256 tile, BK=32, 8 waves (2M x 4N), ring-4 LDS 128KB
#define BM    256
#define BN    256
#define BK    32
#define NT    (D_K / BK)        // 32 K-steps
#define SLOT  16384             // 256 rows x 32 bf16 x 2B per slot

typedef __bf16 bf16x8 __attribute__((ext_vector_type(8)));
typedef float  f32x4  __attribute__((ext_vector_type(4)));

#define GL(p) ((const __attribute__((address_space(1))) void*)(p))
#define LD(p) ((__attribute__((address_space(3))) void*)(p))

__device__ __forceinline__ ushort bfc(float x) {
    __bf16 b = (__bf16)x;
    return __builtin_bit_cast(ushort, b);
}

// Paired-row swizzle (r8-verified 0 conflicts): (row,kb) -> (row>>1)*128 +
// (row&1)*64 + kb, XOR byte bits 4-6 with pseudo-row bits 0-2. Involution.
__device__ __forceinline__ unsigned swz(unsigned x) {
    return x ^ (((x >> 7) & 7u) << 4);
}

// ---------------- fused prep: A f32->bf16, W transpose+pad, bias/Wc pad, zero scores ----
__global__ __launch_bounds__(256) void prep_all(const float* __restrict__ hs,
                                                const float* __restrict__ Wd,
                                                const float* __restrict__ bd,
                                                const float* __restrict__ Wh,
                                                const float* __restrict__ bh,
                                                const float* __restrict__ Wc,
                                                ushort* __restrict__ A,
                                                ushort* __restrict__ Bt,
                                                float* __restrict__ bias_pad,
                                                float* __restrict__ wc_pad,
                                                float4* __restrict__ zero_area) {
    __shared__ ushort tbuf[64][72];
    const int bid = blockIdx.x, tid = threadIdx.x;
    if (bid < 2048) {
        const float4* in = (const float4*)hs;
        const int n4 = ROWS * D_K / 4;
        for (int i = bid * 256 + tid; i < n4; i += 2048 * 256) {
            float4 f = in[i];
            ushort4 o;
            o.x = bfc(f.x); o.y = bfc(f.y); o.z = bfc(f.z); o.w = bfc(f.w);
            ((ushort4*)A)[i] = o;
        }
    } else if (bid < 2304) {
        int b = bid - 2048;
        const int z = b >> 7; b &= 127;
        const int kx = b & 15, ny = b >> 4;
        const float* W = z ? Wh : Wd;
        const int k0 = kx * 64, n0 = ny * 64;
        const int c = tid & 63, r4 = tid >> 6;
        for (int r = r4; r < 64; r += 4) {
            int n = n0 + c;
            float v = (n < MLP) ? W[(size_t)(k0 + r) * MLP + n] : 0.f;
            tbuf[c][r] = bfc(v);
        }
        __syncthreads();
        const int nbase = z * 512 + n0;
        for (int rr = r4; rr < 64; rr += 4)
            Bt[(size_t)(nbase + rr) * D_K + k0 + c] = tbuf[rr][c];
    } else if (bid < 2308) {
        int n = (bid - 2304) * 256 + tid;   // [0,1024)
        float bv = 0.f, w0 = 0.f, w1 = 0.f;
        if (n < 512) {
            if (n < MLP) { bv = bd[n]; w0 = Wc[n * 2]; w1 = Wc[n * 2 + 1]; }
        } else {
            int m = n - 512;
            if (m < MLP) { bv = bh[m]; w0 = Wc[(MLP + m) * 2]; w1 = Wc[(MLP + m) * 2 + 1]; }
        }
        bias_pad[n] = bv; wc_pad[n * 2] = w0; wc_pad[n * 2 + 1] = w1;
    } else {
        int i = (bid - 2308) * 256 + tid;   // [0,16384) float4
        zero_area[i] = make_float4(0.f, 0.f, 0.f, 0.f);
    }
}

// ---------------- 256x256 GEMM, ring-4, stage-3-ahead, counted vmcnt (never 0) ----------
// Per K-step s (slot = s&3), 2 phases:
//   ph0: ds_read 4 B-frags + 4 A-frags(m0-3) | STAGE(s+3) 4 gloads | bar,lgkm0,16 MFMA,bar
//   ph1: ds_read 4 A-frags(m4-7)             | vmcnt(8)            | bar,lgkm0,16 MFMA,bar
// vmcnt ledger: outstanding after ph0 = 12 (steps s+1,s+2,s+3); ph1 vmcnt(8) drains
// s+1 (issued 5 phases earlier), keeps s+2/s+3 in flight. Tail 8->4->0.
// WAR: slot (s+3)&3 = (s-1)&3; its readers retired at lgkm0 >= 2 barriers earlier.
__global__ __launch_bounds__(512) void gemm_scores(const ushort* __restrict__ A,
                                                   const ushort* __restrict__ Bt,
                                                   const float* __restrict__ bias,
                                                   const float* __restrict__ wc,
                                                   float* __restrict__ sd,
                                                   float* __restrict__ sh) {
    __shared__ ushort As[4 * 8192];   // 64 KB
    __shared__ ushort Bs[4 * 8192];   // 64 KB
    const int tid  = threadIdx.x;
    const int lane = tid & 63;
    const int wave = tid >> 6;            // 0..7
    const int wm = wave >> 2, wn = wave & 3;

    // XCD-aware bijective swizzle: 256 blocks -> 32 consecutive per XCD.
    const int flat  = blockIdx.y * gridDim.x + blockIdx.x;
    const int sflat = (flat & 7) * 32 + (flat >> 3);
    const int bn = sflat & 3, bm = sflat >> 2;
    const size_t row0 = (size_t)bm * BM;
    const int col0 = bn * BN;

    char* AsB = (char*)As;
    char* BsB = (char*)Bs;

    // Staging (gload_lds): linear dest, inverse-swizzled source. 2 x 16B/thread/operand.
    const ushort* asrc[2]; const ushort* bsrc[2];
    unsigned ldst[2];
#pragma unroll
    for (int i = 0; i < 2; ++i) {
        unsigned x = (unsigned)i * 8192u + (unsigned)tid * 16u;
        ldst[i] = x;
        unsigned sx = swz(x);
        unsigned row = (sx >> 7) * 2 + ((sx >> 6) & 1);
        unsigned kb  = sx & 63;
        asrc[i] = A  + (row0 + row) * D_K + (kb >> 1);
        bsrc[i] = Bt + (size_t)((unsigned)col0 + row) * D_K + (kb >> 1);
    }

    // Fragment read offsets (r8-verified pattern).
    const unsigned l15 = lane & 15, c16 = (unsigned)(lane >> 4) * 16u;
    unsigned yA[8], yB[4];
#pragma unroll
    for (int m = 0; m < 8; ++m) {
        unsigned R = (unsigned)(wm * 128 + m * 16) + l15;
        yA[m] = swz((R >> 1) * 128u + (R & 1) * 64u + c16);
    }
#pragma unroll
    for (int n = 0; n < 4; ++n) {
        unsigned C = (unsigned)(wn * 64 + n * 16) + l15;
        yB[n] = swz((C >> 1) * 128u + (C & 1) * 64u + c16);
    }

    f32x4 acc[8][4] = {};

#define STAGE(s) { char* dA = AsB + ((s) & 3) * SLOT; char* dB = BsB + ((s) & 3) * SLOT;   \
    __builtin_amdgcn_global_load_lds(GL(asrc[0] + (s) * BK), LD(dA + ldst[0]), 16, 0, 0);  \
    __builtin_amdgcn_global_load_lds(GL(bsrc[0] + (s) * BK), LD(dB + ldst[0]), 16, 0, 0);  \
    __builtin_amdgcn_global_load_lds(GL(asrc[1] + (s) * BK), LD(dA + ldst[1]), 16, 0, 0);  \
    __builtin_amdgcn_global_load_lds(GL(bsrc[1] + (s) * BK), LD(dB + ldst[1]), 16, 0, 0); }

#define PH_TAIL(MQ)                                                                        \
    __builtin_amdgcn_s_barrier();                                                          \
    asm volatile("s_waitcnt lgkmcnt(0)" ::: "memory");                                     \
    __builtin_amdgcn_sched_barrier(0);                                                     \
    __builtin_amdgcn_s_setprio(1);                                                         \
    _Pragma("unroll") for (int m = 0; m < 4; ++m)                                          \
        _Pragma("unroll") for (int n = 0; n < 4; ++n)                                      \
            acc[(MQ) * 4 + m][n] =                                                         \
                __builtin_amdgcn_mfma_f32_16x16x32_bf16(af[m], bf[n], acc[(MQ) * 4 + m][n], 0, 0, 0); \
    __builtin_amdgcn_s_setprio(0);                                                         \
    __builtin_amdgcn_sched_barrier(0);                                                     \
    __builtin_amdgcn_s_barrier();

    // Prologue: steps 0-2 staged (12 outstanding); drain step 0 only.
    STAGE(0); STAGE(1); STAGE(2);
    asm volatile("s_waitcnt vmcnt(8)" ::: "memory");
    __builtin_amdgcn_s_barrier();

#pragma unroll 1
    for (int s = 0; s < NT; ++s) {
        char* Asl = AsB + (s & 3) * SLOT;
        char* Bsl = BsB + (s & 3) * SLOT;
        bf16x8 af[4], bf[4];

        // ph0: B frags + A(m0-3); stage step s+3
#pragma unroll
        for (int n = 0; n < 4; ++n) bf[n] = *(const bf16x8*)(Bsl + yB[n]);
#pragma unroll
        for (int m = 0; m < 4; ++m) af[m] = *(const bf16x8*)(Asl + yA[m]);
        if (s + 3 < NT) STAGE(s + 3);
        PH_TAIL(0)

        // ph1: A(m4-7); counted drain of step s+1
#pragma unroll
        for (int m = 0; m < 4; ++m) af[m] = *(const bf16x8*)(Asl + yA[m + 4]);
        if (s + 3 < NT)      { asm volatile("s_waitcnt vmcnt(8)" ::: "memory"); }
        else if (s + 2 < NT) { asm volatile("s_waitcnt vmcnt(4)" ::: "memory"); }
        else if (s + 1 < NT) { asm volatile("s_waitcnt vmcnt(0)" ::: "memory"); }
        PH_TAIL(1)
    }
#undef STAGE
#undef PH_TAIL

    // Epilogue: bias + leakyrelu + rank-2 contraction, 16-lane reduce, atomic add.
    // C/D layout: col = lane&15, row = (lane>>4)*4 + reg  [m89-verified]
    float bv[4], w0v[4], w1v[4];
#pragma unroll
    for (int nf = 0; nf < 4; ++nf) {
        int cc = col0 + wn * 64 + nf * 16 + (int)l15;
        bv[nf] = bias[cc]; w0v[nf] = wc[2 * cc]; w1v[nf] = wc[2 * cc + 1];
    }
    float* S = (bn < 2) ? sd : sh;
#pragma unroll
    for (int mf = 0; mf < 8; ++mf) {
        size_t rowb = row0 + (size_t)(wm * 128 + mf * 16 + (lane >> 4) * 4);
#pragma unroll
        for (int r = 0; r < 4; ++r) {
            float s0 = 0.f, s1 = 0.f;
#pragma unroll
            for (int nf = 0; nf < 4; ++nf) {
                float h = acc[mf][nf][r] + bv[nf];
                h = (h > 0.f) ? h : NEG * h;
                s0 += h * w0v[nf]; s1 += h * w1v[nf];
            }
#pragma unroll
            for (int m = 1; m < 16; m <<= 1) {
                s0 += __shfl_xor(s0, m, 64);
                s1 += __shfl_xor(s1, m, 64);
            }
            if (l15 == 0) {
                atomicAdd(&S[(rowb + r) * 2 + 0], s0);
                atomicAdd(&S[(rowb + r) * 2 + 1], s1);
            }
        }
    }
}

// ---------------- broadcast add: out[b,i,j,c] = sd[b,i,c] + sh[b,j,c] + bc[c] ----------------
__global__ __launch_bounds__(256) void bcast(const float* __restrict__ sd,
                                             const float* __restrict__ sh,
                                             const float* __restrict__ bc,
                                             float* __restrict__ out) {
    const int bi = blockIdx.x;            // b*1024 + i
    const int b  = bi >> 10;
    const float v0 = sd[bi * 2 + 0] + bc[0];
    const float v1 = sd[bi * 2 + 1] + bc[1];
    const f32x4* shrow = (const f32x4*)(sh + (size_t)b * 2048);
    f32x4* orow = (f32x4*)(out + (size_t)bi * 2048);
#pragma unroll
    for (int t = threadIdx.x; t < 512; t += 256) {
        f32x4 s = shrow[t];
        f32x4 o;
        o.x = v0 + s.x; o.y = v1 + s.y; o.z = v0 + s.z; o.w = v1 + s.w;
        __builtin_nontemporal_store(o, &orow[t]);
    }
}

extern "C" void kernel_launch(void* const* d_in, const int* in_sizes, int n_in,
                              void* d_out, int out_size, void* d_ws, size_t ws_size,
                              hipStream_t stream) {
    const float* hs = (const float*)d_in[0];
    const float* Wd = (const float*)d_in[1];
    const float* bd = (const float*)d_in[2];
    const float* Wh = (const float*)d_in[3];
    const float* bh = (const float*)d_in[4];
    const float* Wc = (const float*)d_in[5];
    const float* bc = (const float*)d_in[6];
    float* out = (float*)d_out;

    char* ws = (char*)d_ws;
    ushort* A    = (ushort*)(ws);                 // 33,554,432 B
    ushort* Bt   = (ushort*)(ws + 33554432);      //  2,097,152 B
    float*  bias = (float*) (ws + 35651584);      //  4 KB
    float*  wcp  = (float*) (ws + 35655680);      //  8 KB
    float*  sd   = (float*) (ws + 35663872);      //  128 KB
    float*  sh   = (float*) (ws + 35794944);      //  128 KB

    prep_all<<<2372, 256, 0, stream>>>(hs, Wd, bd, Wh, bh, Wc, A, Bt, bias, wcp, (float4*)sd);
    gemm_scores<<<dim3(4, 64), 512, 0, stream>>>(A, Bt, bias, wcp, sd, sh);
    bcast<<<ROWS, 256, 0, stream>>>(sd, sh, bc, out);
}

// Round 13
// 89.900 us; speedup vs baseline: 1.1054x; 1.1054x over previous
//
#include <hip/hip_runtime.h>

// Problem constants
#define D_K   1024      // hidden dim (GEMM K)
#define ROWS  16384     // B*L
#define MLP   500
#define NEG   0.01f

// GEMM geometry
#define BM    256
#define BN    256
#define BK    32
#define NT    (D_K / BK)        // 32 K-tiles
#define SLOT_B (BM * BK * 2)    // 16384 bytes per tile per matrix

typedef __bf16 bf16x8 __attribute__((ext_vector_type(8)));
typedef __bf16 bf16x4 __attribute__((ext_vector_type(4)));
typedef float  f32x4  __attribute__((ext_vector_type(4)));

#define GL(p) ((const __attribute__((address_space(1))) void*)(p))
#define LD(p) ((__attribute__((address_space(3))) void*)(p))

// f32 -> bf16 RNE via hw cvt
__device__ __forceinline__ ushort bfc(float x) {
    __bf16 b = (__bf16)x;
    return __builtin_bit_cast(ushort, b);
}

// T2 swizzle (r2-r7-verified involution): XOR byte bits 4-5 with bits 7-8.
__device__ __forceinline__ unsigned swz(unsigned x) {
    return x ^ (((x >> 7) & 3u) << 4);
}

// ---------------- prep-lite: W transpose+pad, bias/Wc pad, zero scores ----------------
__global__ __launch_bounds__(256) void prep_lite(const float* __restrict__ Wd,
                                                 const float* __restrict__ bd,
                                                 const float* __restrict__ Wh,
                                                 const float* __restrict__ bh,
                                                 const float* __restrict__ Wc,
                                                 ushort* __restrict__ Bt,
                                                 float* __restrict__ bias_pad,
                                                 float* __restrict__ wc_pad,
                                                 float4* __restrict__ zero_area) {
    __shared__ ushort tbuf[64][72];
    const int bid = blockIdx.x, tid = threadIdx.x;
    if (bid < 256) {
        // W [1024][500] -> Bt bf16 [1024][1024] transposed + zero-padded
        int b = bid;
        const int z = b >> 7; b &= 127;
        const int kx = b & 15, ny = b >> 4;
        const float* W = z ? Wh : Wd;
        const int k0 = kx * 64, n0 = ny * 64;
        const int c = tid & 63, r4 = tid >> 6;
        for (int r = r4; r < 64; r += 4) {
            int n = n0 + c;
            float v = (n < MLP) ? W[(size_t)(k0 + r) * MLP + n] : 0.f;
            tbuf[c][r] = bfc(v);
        }
        __syncthreads();
        const int nbase = z * 512 + n0;
        for (int rr = r4; rr < 64; rr += 4)
            Bt[(size_t)(nbase + rr) * D_K + k0 + c] = tbuf[rr][c];
    } else if (bid < 260) {
        // pad bias + Wc
        int n = (bid - 256) * 256 + tid;   // [0,1024)
        float bv = 0.f, w0 = 0.f, w1 = 0.f;
        if (n < 512) {
            if (n < MLP) { bv = bd[n]; w0 = Wc[n * 2]; w1 = Wc[n * 2 + 1]; }
        } else {
            int m = n - 512;
            if (m < MLP) { bv = bh[m]; w0 = Wc[(MLP + m) * 2]; w1 = Wc[(MLP + m) * 2 + 1]; }
        }
        bias_pad[n] = bv; wc_pad[n * 2] = w0; wc_pad[n * 2 + 1] = w1;
    } else {
        // zero sd+sh (256 KB contiguous)
        int i = (bid - 260) * 256 + tid;   // [0,16384) float4
        zero_area[i] = make_float4(0.f, 0.f, 0.f, 0.f);
    }
}

// ---------------- 256x256 GEMM, fused f32->bf16 A-staging, 2 barriers/tile ----------------
// r7 base; ONE change: ALOAD moved to phase B at distance t+4 (2 full K-steps ahead of
// its AWRITE consumer), phase-B issue order AWRITE(t+2) -> BSTAGE(t+3) -> ALOAD(t+4).
// Hazard ledger:
//  - RAW B[t]: BSTAGE(t)@t-3.phB precedes ALOAD(t+1)@t-3.phB => drained by AWRITE(t+1)@t-1's
//    implicit wait (in-order retirement), >=1 barrier before t.phA readers.
//  - RAW A[t]: AWRITE(t)@t-2.phB ds_writes forced by that wave's post-bar lgkm0, >=2
//    barriers before t.phA readers.
//  - WAR A-slot (t+2)&3 / B-slot (t+3)&3: readers retired >=2 barriers earlier.
//  - R-buffer: AWRITE(t+2) reads R[t&1]; ALOAD(t+4) rewrites the same R after (program order).
//  - Tail: explicit vmcnt(0) at t+2>=NT drains BSTAGE(NT-1)@NT-4 before NT-1.phA reads.
__global__ __launch_bounds__(512) void gemm_scores(const float* __restrict__ hs,
                                                   const ushort* __restrict__ Bt,
                                                   const float* __restrict__ bias,
                                                   const float* __restrict__ wc,
                                                   float* __restrict__ sd,
                                                   float* __restrict__ sh) {
    __shared__ ushort As[4 * BM * BK];   // 64 KB
    __shared__ ushort Bs[4 * BN * BK];   // 64 KB
    const int tid  = threadIdx.x;
    const int lane = tid & 63;
    const int wave = tid >> 6;            // 0..7
    const int wm = wave >> 2, wn = wave & 3;

    // XCD-aware bijective swizzle: 32 consecutive sflat per XCD -> the 4
    // bn-blocks sharing an A panel (and its hs f32 source) on one XCD's L2.
    const int flat  = blockIdx.y * gridDim.x + blockIdx.x;
    const int sflat = (flat & 7) * 32 + (flat >> 3);
    const int bn = sflat & 3, bm = sflat >> 2;
    const size_t row0 = (size_t)bm * BM;
    const int col0 = bn * BN;

    char* AsB = (char*)As;
    char* BsB = (char*)Bs;

    // B staging (gload_lds): linear LDS dest, inverse-swizzled global source.
    const ushort* bptr[2];
    unsigned ldst[2];
#pragma unroll
    for (int i = 0; i < 2; ++i) {
        unsigned x = (unsigned)wave * 1024u + (unsigned)i * 8192u + (unsigned)lane * 16u;
        ldst[i] = x;
        unsigned sx = swz(x);
        unsigned row = sx >> 6, cb = sx & 63;
        bptr[i] = Bt + (size_t)((unsigned)col0 + row) * D_K + (cb >> 1);
    }

    // A reg-staging addressing: thread covers row r = tid>>1, 64B-f32 half h = tid&1.
    const int ar = tid >> 1, ah = tid & 1;
    const f32x4* hsp = (const f32x4*)hs;
    const unsigned aof = (unsigned)((row0 + ar) * 256 + ah * 4);
    unsigned awx[2];
#pragma unroll
    for (int j = 0; j < 2; ++j)
        awx[j] = swz((unsigned)ar * 64u + (unsigned)ah * 32u + (unsigned)j * 16u);

    // ds_read fragment offsets (swizzled)
    const unsigned l15 = lane & 15, c16 = (unsigned)(lane >> 4) * 16u;
    unsigned yA[8], yB[4];
#pragma unroll
    for (int m = 0; m < 8; ++m) yA[m] = swz(((unsigned)(wm * 128 + m * 16) + l15) * 64u + c16);
#pragma unroll
    for (int n = 0; n < 4; ++n) yB[n] = swz(((unsigned)(wn * 64 + n * 16) + l15) * 64u + c16);

    f32x4 acc[8][4] = {};
    f32x4 R0[4], R1[4];

#define BSTAGE(t) { const int sl_ = (t) & 3;                                                              \
    __builtin_amdgcn_global_load_lds(GL(bptr[0] + (t) * BK), LD(BsB + sl_ * SLOT_B + ldst[0]), 16, 0, 0); \
    __builtin_amdgcn_global_load_lds(GL(bptr[1] + (t) * BK), LD(BsB + sl_ * SLOT_B + ldst[1]), 16, 0, 0); }
#define ALOAD(R, t) { _Pragma("unroll")                                                                   \
    for (int j = 0; j < 4; ++j) R[j] = hsp[aof + (t) * 8 + j]; }
#define AWRITE(R, t) { const int sl_ = (t) & 3; _Pragma("unroll")                                         \
    for (int j = 0; j < 2; ++j) {                                                                         \
        bf16x4 a_ = __builtin_convertvector(R[2 * j],     bf16x4);                                        \
        bf16x4 b_ = __builtin_convertvector(R[2 * j + 1], bf16x4);                                        \
        bf16x8 w_ = __builtin_shufflevector(a_, b_, 0, 1, 2, 3, 4, 5, 6, 7);                              \
        *(bf16x8*)(AsB + sl_ * SLOT_B + awx[j]) = w_; } }

    // Prologue: B slots 0-2 staged; A slots 0-1 written; R0/R1 hold tiles 2/3.
    BSTAGE(0); BSTAGE(1); BSTAGE(2);
    ALOAD(R0, 0); ALOAD(R1, 1);
    AWRITE(R0, 0);      // implicit wait on ALOAD(0)/(1) drains BSTAGE(0-2) too
    AWRITE(R1, 1);
    ALOAD(R0, 2); ALOAD(R1, 3);
    asm volatile("s_waitcnt lgkmcnt(0)" ::: "memory");
    __builtin_amdgcn_s_barrier();

    // TILE(t): phase A {frags m0-3 + B, bar, MFMA m0-3}
    //          phase B {frags m4-7, AWRITE(t+2), BSTAGE(t+3), ALOAD(t+4), bar, MFMA m4-7}
#define TILE(t, Rw) {                                                                     \
    const int sl = (t) & 3;                                                               \
    char* Asl = AsB + sl * SLOT_B;                                                        \
    char* Bsl = BsB + sl * SLOT_B;                                                        \
    bf16x8 bf[4], af[4];                                                                  \
    _Pragma("unroll") for (int n = 0; n < 4; ++n) bf[n] = *(const bf16x8*)(Bsl + yB[n]);  \
    _Pragma("unroll") for (int m = 0; m < 4; ++m) af[m] = *(const bf16x8*)(Asl + yA[m]);  \
    __builtin_amdgcn_s_barrier();                                                         \
    asm volatile("s_waitcnt lgkmcnt(0)" ::: "memory");                                    \
    __builtin_amdgcn_sched_barrier(0);                                                    \
    __builtin_amdgcn_s_setprio(1);                                                        \
    _Pragma("unroll") for (int m = 0; m < 4; ++m)                                         \
        _Pragma("unroll") for (int n = 0; n < 4; ++n)                                     \
            acc[m][n] = __builtin_amdgcn_mfma_f32_16x16x32_bf16(af[m], bf[n], acc[m][n], 0, 0, 0); \
    __builtin_amdgcn_s_setprio(0);                                                        \
    __builtin_amdgcn_sched_barrier(0);                                                    \
    bf16x8 ag[4];                                                                         \
    _Pragma("unroll") for (int m = 0; m < 4; ++m) ag[m] = *(const bf16x8*)(Asl + yA[m + 4]); \
    if ((t) + 2 < NT) AWRITE(Rw, (t) + 2);                                                \
    if ((t) + 3 < NT) BSTAGE((t) + 3);                                                    \
    if ((t) + 4 < NT) ALOAD(Rw, (t) + 4);                                                 \
    if ((t) + 2 >= NT) asm volatile("s_waitcnt vmcnt(0)" ::: "memory");                   \
    __builtin_amdgcn_s_barrier();                                                         \
    asm volatile("s_waitcnt lgkmcnt(0)" ::: "memory");                                    \
    __builtin_amdgcn_sched_barrier(0);                                                    \
    __builtin_amdgcn_s_setprio(1);                                                        \
    _Pragma("unroll") for (int m = 0; m < 4; ++m)                                         \
        _Pragma("unroll") for (int n = 0; n < 4; ++n)                                     \
            acc[m + 4][n] = __builtin_amdgcn_mfma_f32_16x16x32_bf16(ag[m], bf[n], acc[m + 4][n], 0, 0, 0); \
    __builtin_amdgcn_s_setprio(0);                                                        \
    __builtin_amdgcn_sched_barrier(0); }

    for (int t = 0; t < NT; t += 2) {
        TILE(t,     R0);   // AWRITE(t+2) from R0; ALOAD(t+4) -> R0
        TILE(t + 1, R1);   // AWRITE(t+3) from R1; ALOAD(t+5) -> R1
    }
#undef TILE
#undef BSTAGE
#undef ALOAD
#undef AWRITE

    // Epilogue: bias + leakyrelu + rank-2 contraction, 16-lane reduce, atomic add.
    // C/D layout: col = lane&15, row = (lane>>4)*4 + reg  [m89-verified]
    float bv[4], w0v[4], w1v[4];
#pragma unroll
    for (int nf = 0; nf < 4; ++nf) {
        int cc = col0 + wn * 64 + nf * 16 + (int)l15;
        bv[nf] = bias[cc]; w0v[nf] = wc[2 * cc]; w1v[nf] = wc[2 * cc + 1];
    }
    float* S = (bn < 2) ? sd : sh;
#pragma unroll
    for (int mf = 0; mf < 8; ++mf) {
        size_t rowb = row0 + (size_t)(wm * 128 + mf * 16 + (lane >> 4) * 4);
#pragma unroll
        for (int r = 0; r < 4; ++r) {
            float s0 = 0.f, s1 = 0.f;
#pragma unroll
            for (int nf = 0; nf < 4; ++nf) {
                float h = acc[mf][nf][r] + bv[nf];
                h = (h > 0.f) ? h : NEG * h;
                s0 += h * w0v[nf]; s1 += h * w1v[nf];
            }
#pragma unroll
            for (int m = 1; m < 16; m <<= 1) {
                s0 += __shfl_xor(s0, m, 64);
                s1 += __shfl_xor(s1, m, 64);
            }
            if (l15 == 0) {
                atomicAdd(&S[(rowb + r) * 2 + 0], s0);
                atomicAdd(&S[(rowb + r) * 2 + 1], s1);
            }
        }
    }
}

// ---------------- broadcast add: out[b,i,j,c] = sd[b,i,c] + sh[b,j,c] + bc[c] ----------------
__global__ __launch_bounds__(256) void bcast(const float* __restrict__ sd,
                                             const float* __restrict__ sh,
                                             const float* __restrict__ bc,
                                             float* __restrict__ out) {
    const int bi = blockIdx.x;            // b*1024 + i
    const int b  = bi >> 10;
    const float v0 = sd[bi * 2 + 0] + bc[0];
    const float v1 = sd[bi * 2 + 1] + bc[1];
    const f32x4* shrow = (const f32x4*)(sh + (size_t)b * 2048);
    f32x4* orow = (f32x4*)(out + (size_t)bi * 2048);
#pragma unroll
    for (int t = threadIdx.x; t < 512; t += 256) {
        f32x4 s = shrow[t];
        f32x4 o;
        o.x = v0 + s.x; o.y = v1 + s.y; o.z = v0 + s.z; o.w = v1 + s.w;
        __builtin_nontemporal_store(o, &orow[t]);
    }
}

extern "C" void kernel_launch(void* const* d_in, const int* in_sizes, int n_in,
                              void* d_out, int out_size, void* d_ws, size_t ws_size,
                              hipStream_t stream) {
    const float* hs = (const float*)d_in[0];
    const float* Wd = (const float*)d_in[1];
    const float* bd = (const float*)d_in[2];
    const float* Wh = (const float*)d_in[3];
    const float* bh = (const float*)d_in[4];
    const float* Wc = (const float*)d_in[5];
    const float* bc = (const float*)d_in[6];
    float* out = (float*)d_out;

    char* ws = (char*)d_ws;
    ushort* Bt   = (ushort*)(ws);                 // 2,097,152 B
    float*  bias = (float*) (ws + 2097152);       // 4 KB
    float*  wcp  = (float*) (ws + 2101248);       // 8 KB
    float*  sd   = (float*) (ws + 2109440);       // 128 KB
    float*  sh   = (float*) (ws + 2240512);       // 128 KB (contiguous after sd)

    prep_lite<<<324, 256, 0, stream>>>(Wd, bd, Wh, bh, Wc, Bt, bias, wcp, (float4*)sd);
    gemm_scores<<<dim3(4, 64), 512, 0, stream>>>(hs, Bt, bias, wcp, sd, sh);
    bcast<<<ROWS, 256, 0, stream>>>(sd, sh, bc, out);
}